// Round 1
// baseline (93.164 us; speedup 1.0000x reference)
//
#include <hip/hip_runtime.h>
#include <math.h>

// Problem constants (from reference)
#define B_N    256   // batch
#define IN_N   512   // in_dim
#define H_N    256   // hidden
#define D_N    16    // out_dim
#define M_N    64    // num particles

// ---------------------------------------------------------------------------
// Kernel 1: prep
//   W2m[k][d] = mean_m W2[k][d*64+m]   (256 x 16)
//   b2m[d]    = mean_m b2[d*64+m]      (16)
//   out[0]    = 0                      (d_out is poisoned 0xAA; zero for atomicAdd)
// Grid: 16 blocks x 256 threads = 4096 threads (one per (k,d))
// ---------------------------------------------------------------------------
__global__ __launch_bounds__(256) void prep_kernel(
    const float* __restrict__ W2, const float* __restrict__ b2,
    float* __restrict__ W2m, float* __restrict__ b2m, float* __restrict__ out)
{
    int t = blockIdx.x * 256 + threadIdx.x;   // 0..4095
    int k = t >> 4;
    int d = t & 15;
    const float* p = W2 + (size_t)k * (D_N * M_N) + d * M_N;  // 256B-aligned
    float s = 0.f;
    #pragma unroll
    for (int m = 0; m < M_N; m += 4) {
        float4 v = *(const float4*)(p + m);
        s += (v.x + v.y) + (v.z + v.w);
    }
    W2m[k * D_N + d] = s * (1.0f / M_N);

    if (blockIdx.x == 0 && threadIdx.x < D_N) {
        int dd = threadIdx.x;
        float sb = 0.f;
        #pragma unroll
        for (int m = 0; m < M_N; ++m) sb += b2[dd * M_N + m];
        b2m[dd] = sb * (1.0f / M_N);
    }
    if (blockIdx.x == 0 && threadIdx.x == 0) out[0] = 0.f;
}

// ---------------------------------------------------------------------------
// Kernel 2: h = tanh(x @ W1 + b1)   [256 x 256]
// One block per batch row b; thread j computes h[b][j].
// x row staged in LDS (broadcast reads are conflict-free);
// W1[k*256 + j] reads are fully coalesced across the wave.
// ---------------------------------------------------------------------------
__global__ __launch_bounds__(256) void hidden_kernel(
    const float* __restrict__ x, const float* __restrict__ W1,
    const float* __restrict__ b1, float* __restrict__ h)
{
    __shared__ float xs[IN_N];
    int b = blockIdx.x;
    int j = threadIdx.x;

    // 256 threads x float2 = 512 floats
    ((float2*)xs)[j] = ((const float2*)(x + (size_t)b * IN_N))[j];
    __syncthreads();

    float acc = b1[j];
    #pragma unroll 8
    for (int k = 0; k < IN_N; ++k) {
        acc = fmaf(xs[k], W1[(size_t)k * H_N + j], acc);
    }
    h[(size_t)b * H_N + j] = tanhf(acc);
}

// ---------------------------------------------------------------------------
// Kernel 3: mean_fake = h @ W2m + b2m; loss += 0.5/B * sum((mf - y)^2)
// 16 blocks x 256 threads; thread (b_local = t>>4, d = t&15) handles one (b,d).
// W2m staged in LDS (16 KB). Block-reduce then one atomicAdd per block.
// ---------------------------------------------------------------------------
__global__ __launch_bounds__(256) void loss_kernel(
    const float* __restrict__ h, const float* __restrict__ y,
    const float* __restrict__ W2m, const float* __restrict__ b2m,
    float* __restrict__ out)
{
    __shared__ float w2s[H_N * D_N];   // 4096 floats = 16 KB
    int t = threadIdx.x;
    #pragma unroll
    for (int i = 0; i < 16; ++i) w2s[i * 256 + t] = W2m[i * 256 + t];
    __syncthreads();

    int bl = t >> 4;
    int d  = t & 15;
    int b  = blockIdx.x * 16 + bl;
    const float* hp = h + (size_t)b * H_N;

    float acc = b2m[d];
    #pragma unroll 8
    for (int k = 0; k < H_N; ++k) {
        acc = fmaf(hp[k], w2s[k * D_N + d], acc);
    }
    float diff = acc - y[(size_t)b * D_N + d];
    float c = (0.5f / (float)B_N) * diff * diff;

    // wave64 reduce
    #pragma unroll
    for (int off = 32; off >= 1; off >>= 1) c += __shfl_down(c, off, 64);

    __shared__ float red[4];
    if ((t & 63) == 0) red[t >> 6] = c;
    __syncthreads();
    if (t == 0) {
        atomicAdd(out, (red[0] + red[1]) + (red[2] + red[3]));
    }
}

// ---------------------------------------------------------------------------
extern "C" void kernel_launch(void* const* d_in, const int* in_sizes, int n_in,
                              void* d_out, int out_size, void* d_ws, size_t ws_size,
                              hipStream_t stream)
{
    const float* x  = (const float*)d_in[0];  // [256,512]
    const float* y  = (const float*)d_in[1];  // [256,16]
    const float* W1 = (const float*)d_in[2];  // [512,256]
    const float* b1 = (const float*)d_in[3];  // [256]
    const float* W2 = (const float*)d_in[4];  // [256,1024]
    const float* b2 = (const float*)d_in[5];  // [1024]
    float* out = (float*)d_out;               // scalar loss

    // Workspace layout (floats): h[256*256] | W2m[256*16] | b2m[16]
    float* h   = (float*)d_ws;
    float* W2m = h + B_N * H_N;
    float* b2m = W2m + H_N * D_N;

    prep_kernel<<<16, 256, 0, stream>>>(W2, b2, W2m, b2m, out);
    hidden_kernel<<<B_N, 256, 0, stream>>>(x, W1, b1, h);
    loss_kernel<<<B_N / 16, 256, 0, stream>>>(h, y, W2m, b2m, out);
}

// Round 2
// 83.037 us; speedup vs baseline: 1.1219x; 1.1219x over previous
//
#include <hip/hip_runtime.h>
#include <math.h>

// Problem constants (from reference)
#define B_N    256   // batch
#define IN_N   512   // in_dim
#define H_N    256   // hidden
#define D_N    16    // out_dim
#define M_N    64    // num particles

// Round-to-nearest-even fp32 -> bf16 (as uint16 in low bits)
__device__ __forceinline__ unsigned int f2bf(float f) {
    unsigned int b = __float_as_uint(f);
    return (b + 0x7FFFu + ((b >> 16) & 1u)) >> 16;
}

// ---------------------------------------------------------------------------
// Kernel 1: prep (80 blocks x 256 threads)
//   blocks 0..63 : pack W1 (fp32 [512][256]) into bf16 pairs
//                  W1p[kk*256 + j] = (bf16(W1[2kk][j]), bf16(W1[2kk+1][j]))
//                  (reads and writes fully coalesced; no transpose needed)
//   blocks 64..79: W2m[k*16+d] = mean_m W2[k][d*64+m]; block 64 also does
//                  b2m and zeroes out[0] (poisoned 0xAA, needed for atomicAdd).
// ---------------------------------------------------------------------------
__global__ __launch_bounds__(256) void prep_kernel(
    const float* __restrict__ W1, const float* __restrict__ W2,
    const float* __restrict__ b2,
    unsigned int* __restrict__ W1p, float* __restrict__ W2m,
    float* __restrict__ b2m, float* __restrict__ out)
{
    int t   = threadIdx.x;
    int blk = blockIdx.x;
    if (blk < 64) {
        #pragma unroll
        for (int r = 0; r < 4; ++r) {
            int p  = blk * 1024 + r * 256 + t;   // pair index 0..65535
            int kk = p >> 8;                      // k/2 : 0..255
            int j  = p & 255;                     // hidden col
            float f0 = W1[(size_t)(2 * kk)     * H_N + j];
            float f1 = W1[(size_t)(2 * kk + 1) * H_N + j];
            W1p[p] = f2bf(f0) | (f2bf(f1) << 16);
        }
    } else {
        int tt = (blk - 64) * 256 + t;           // 0..4095 -> (k, d)
        int k = tt >> 4;
        int d = tt & 15;
        const float* pw = W2 + (size_t)k * (D_N * M_N) + d * M_N;
        float s = 0.f;
        #pragma unroll
        for (int m = 0; m < M_N; m += 4) {
            float4 v = *(const float4*)(pw + m);
            s += (v.x + v.y) + (v.z + v.w);
        }
        W2m[k * D_N + d] = s * (1.0f / M_N);

        if (blk == 64 && t < D_N) {
            float sb = 0.f;
            #pragma unroll
            for (int m = 0; m < M_N; ++m) sb += b2[t * M_N + m];
            b2m[t] = sb * (1.0f / M_N);
        }
        if (blk == 64 && t == 0) out[0] = 0.f;
    }
}

// ---------------------------------------------------------------------------
// Kernel 2: fused hidden + loss (256 blocks x 256 threads, one block per b)
//   phase 1: h[j] = tanh(sum_k x[b][k] * W1[k][j] + b1[j])  (bf16 W1, 4 acc
//            chains, float4 LDS x-reads)  -> LDS
//   phase 2: mean_fake[d] = sum_k h[k]*W2m[k][d] + b2m[d]; block partial of
//            0.5/B * (mf - y)^2 -> one atomicAdd per block
// ---------------------------------------------------------------------------
__global__ __launch_bounds__(256) void fused_kernel(
    const float* __restrict__ x, const float* __restrict__ y,
    const unsigned int* __restrict__ W1p, const float* __restrict__ b1,
    const float* __restrict__ W2m, const float* __restrict__ b2m,
    float* __restrict__ out)
{
    __shared__ float xs[IN_N];         // 2 KB
    __shared__ float hs[H_N];          // 1 KB
    __shared__ float w2s[H_N * D_N];   // 16 KB
    __shared__ float part[256];        // 1 KB

    int t = threadIdx.x;
    int b = blockIdx.x;

    ((float2*)xs)[t] = ((const float2*)(x + (size_t)b * IN_N))[t];
    #pragma unroll
    for (int i = 0; i < 16; ++i) w2s[i * 256 + t] = W2m[i * 256 + t];
    __syncthreads();

    // ---- phase 1 ----
    const unsigned int* wp = W1p + t;     // column j = t, stride 256 uints in k/2
    const float4* xs4 = (const float4*)xs;
    float a0 = 0.f, a1 = 0.f, a2 = 0.f, a3 = 0.f;
    #pragma unroll 4
    for (int q = 0; q < 128; ++q) {       // 4 k-values per iter
        float4 xv = xs4[q];
        unsigned int u0 = wp[(2 * q + 0) << 8];
        unsigned int u1 = wp[(2 * q + 1) << 8];
        a0 = fmaf(xv.x, __uint_as_float(u0 << 16),         a0);
        a1 = fmaf(xv.y, __uint_as_float(u0 & 0xFFFF0000u), a1);
        a2 = fmaf(xv.z, __uint_as_float(u1 << 16),         a2);
        a3 = fmaf(xv.w, __uint_as_float(u1 & 0xFFFF0000u), a3);
    }
    hs[t] = tanhf(((a0 + a1) + (a2 + a3)) + b1[t]);
    __syncthreads();

    // ---- phase 2 ----
    int d  = t & 15;
    int kc = t >> 4;                      // 16 k-chunks of 16
    float p = 0.f;
    #pragma unroll
    for (int kk = 0; kk < 16; ++kk) {
        int k = kc * 16 + kk;
        p = fmaf(hs[k], w2s[k * D_N + d], p);
    }
    part[t] = p;                          // part[kc*16 + d]
    __syncthreads();

    if (t < 16) {                         // lanes 0..15 of wave 0
        float mf = b2m[t];
        #pragma unroll
        for (int kc2 = 0; kc2 < 16; ++kc2) mf += part[kc2 * 16 + t];
        float diff = mf - y[(size_t)b * D_N + t];
        float c = diff * diff;
        c += __shfl_down(c, 8, 16);
        c += __shfl_down(c, 4, 16);
        c += __shfl_down(c, 2, 16);
        c += __shfl_down(c, 1, 16);
        if (t == 0) atomicAdd(out, c * (0.5f / (float)B_N));
    }
}

// ---------------------------------------------------------------------------
extern "C" void kernel_launch(void* const* d_in, const int* in_sizes, int n_in,
                              void* d_out, int out_size, void* d_ws, size_t ws_size,
                              hipStream_t stream)
{
    const float* x  = (const float*)d_in[0];  // [256,512]
    const float* y  = (const float*)d_in[1];  // [256,16]
    const float* W1 = (const float*)d_in[2];  // [512,256]
    const float* b1 = (const float*)d_in[3];  // [256]
    const float* W2 = (const float*)d_in[4];  // [256,1024]
    const float* b2 = (const float*)d_in[5];  // [1024]
    float* out = (float*)d_out;               // scalar loss

    // Workspace: W1p (65536 uint) | W2m (4096 f32) | b2m (16 f32)
    unsigned int* W1p = (unsigned int*)d_ws;
    float* W2m = (float*)(W1p + (IN_N / 2) * H_N);
    float* b2m = W2m + H_N * D_N;

    prep_kernel<<<80, 256, 0, stream>>>(W1, W2, b2, W1p, W2m, b2m, out);
    fused_kernel<<<B_N, 256, 0, stream>>>(x, y, W1p, b1, W2m, b2m, out);
}